// Round 10
// baseline (326.853 us; speedup 1.0000x reference)
//
#include <hip/hip_runtime.h>
#include <cfloat>
#include <cmath>

#define NB 2048
#define BB 16
#define DD 128
#define HH 64
#define MAXC 5
#define NT 1024

#define OFF_P 0                          // [BB*NB][HH] 8 MB
#define OFF_PART (OFF_P + BB * NB * HH)  // [BB][16][DD]

// ---------------- Threefry-2x32 (JAX-exact) ----------------
__device__ __forceinline__ unsigned rotl32(unsigned v, int d) {
  return (v << d) | (v >> (32 - d));
}

__device__ __forceinline__ void tf2x32(unsigned k0, unsigned k1, unsigned x0, unsigned x1,
                                       unsigned& o0, unsigned& o1) {
  unsigned ks2 = k0 ^ k1 ^ 0x1BD11BDAu;
  x0 += k0; x1 += k1;
#define RND(r) { x0 += x1; x1 = rotl32(x1, r); x1 ^= x0; }
  RND(13) RND(15) RND(26) RND(6)   x0 += k1;  x1 += ks2 + 1u;
  RND(17) RND(29) RND(16) RND(24)  x0 += ks2; x1 += k0 + 2u;
  RND(13) RND(15) RND(26) RND(6)   x0 += k0;  x1 += k1 + 3u;
  RND(17) RND(29) RND(16) RND(24)  x0 += k1;  x1 += ks2 + 4u;
  RND(13) RND(15) RND(26) RND(6)   x0 += ks2; x1 += k0 + 5u;
#undef RND
  o0 = x0; o1 = x1;
}

__device__ __forceinline__ float gumbel_for(unsigned k0, unsigned k1, unsigned idx) {
  unsigned o0, o1;
  tf2x32(k0, k1, 0u, idx, o0, o1);
  unsigned bits = o0 ^ o1;
  float u = __uint_as_float((bits >> 9) | 0x3f800000u) - 1.0f;
  float uu = u + 1e-8f;
  return -logf(-logf(uu) + 1e-8f);
}

__device__ __forceinline__ unsigned long long packKey(float y, int n) {
  unsigned u = __float_as_uint(y);
  u = (u & 0x80000000u) ? ~u : (u | 0x80000000u);
  return ((unsigned long long)u << 32) | (unsigned)(~(unsigned)n);
}
__device__ __forceinline__ int decodeKey(unsigned long long k) {
  return k ? (int)(~(unsigned)k) : -1;
}

// ---------------- prep: P-GEMM + mean partials ----------------
__global__ __launch_bounds__(1024) void gvp_prep(
    const float* __restrict__ x, const float* __restrict__ W1, float* __restrict__ ws) {
  __shared__ __align__(16) float s_W1[HH][DD + 4];
  __shared__ float sp[8][DD];
  const int bid = blockIdx.x, tid = threadIdx.x;
  float* P = ws + OFF_P;
  float* partial = ws + OFF_PART;

  if (bid < 128) {
    for (int i = tid; i < HH * (DD / 4); i += 1024) {
      int r = i >> 5, q = i & 31;
      *(float4*)&s_W1[r][q * 4] = *(const float4*)(W1 + (size_t)r * (DD + HH) + q * 4);
    }
    __syncthreads();
    const int jg = tid & 15, ng = tid >> 4;
    const int j0 = jg * 4;
    const size_t n0 = (size_t)bid * 256 + ng * 4;
    const float4* x4 = (const float4*)x;
    float acc[4][4];
#pragma unroll
    for (int i = 0; i < 4; i++)
#pragma unroll
      for (int q = 0; q < 4; q++) acc[i][q] = 0.f;
    for (int kq = 0; kq < 32; kq++) {
      float4 xv[4], wv[4];
#pragma unroll
      for (int i = 0; i < 4; i++) xv[i] = x4[(n0 + i) * 32 + kq];
#pragma unroll
      for (int q = 0; q < 4; q++) wv[q] = *(const float4*)&s_W1[j0 + q][kq * 4];
#pragma unroll
      for (int i = 0; i < 4; i++)
#pragma unroll
        for (int q = 0; q < 4; q++)
          acc[i][q] += xv[i].x * wv[q].x + xv[i].y * wv[q].y +
                       xv[i].z * wv[q].z + xv[i].w * wv[q].w;
    }
#pragma unroll
    for (int i = 0; i < 4; i++)
#pragma unroll
      for (int q = 0; q < 4; q++)
        P[(n0 + i) * HH + j0 + q] = acc[i][q];
  } else {
    const int bm = bid - 128;
    const int b = bm >> 4, chunk = bm & 15;
    const int d = tid & (DD - 1), part = tid >> 7;
    float acc = 0.f;
    const int base = chunk * 128 + part;
#pragma unroll
    for (int k = 0; k < 16; k++)
      acc += x[((size_t)b * NB + base + k * 8) * DD + d];
    sp[part][d] = acc;
    __syncthreads();
    if (tid < DD) {
      float m = 0.f;
#pragma unroll
      for (int p = 0; p < 8; p++) m += sp[p][tid];
      partial[((size_t)b * 16 + chunk) * DD + tid] = m;
    }
  }
}

// ---------------- main: 1 block (1024 thr) per batch, 27 barrier-phases ----------------
__global__ __launch_bounds__(NT, 4) void gvp_main(
    const float* __restrict__ x, const float* __restrict__ adj, const int* __restrict__ mask,
    const float* __restrict__ W1, const float* __restrict__ b1,
    const float* __restrict__ W2, const float* __restrict__ b2,
    const float* __restrict__ Wc, const float* __restrict__ bc,
    const float* __restrict__ Wih, const float* __restrict__ Whh,
    const float* __restrict__ bih, const float* __restrict__ bhh,
    const float* __restrict__ ws,
    float* __restrict__ out_feat, float* __restrict__ out_adjm, float* __restrict__ out_assign) {
  const int b = blockIdx.x;
  const int tid = threadIdx.x;
  const int t = tid;

  __shared__ float s_WhhT[HH][3 * HH];   // [k][row] 48 KB (bank = row%32: conflict-free)
  __shared__ float s_W1cT[HH][HH];       // [k][row] 16 KB
  __shared__ unsigned char s_avail[NB], s_assignB[NB];
  __shared__ short s_flist[128];
  __shared__ int s_cnt;
  __shared__ unsigned long long s_key[2];
  __shared__ unsigned long long s_top2[16][2];
  __shared__ __align__(16) float s_giAll[MAXC][3 * HH];
  __shared__ __align__(16) float s_h[HH], s_q[HH], s_ctx[HH];
  __shared__ __align__(16) float s_mean[DD];
  __shared__ float s_bhh[3 * HH], s_b1[HH], s_W2v[HH];
  __shared__ float s_b2v;

  const size_t adjb = (size_t)b * NB * NB;
  const size_t xb = (size_t)b * NB * DD;
  const float4* P4 = (const float4*)(ws + OFF_P) + (size_t)b * NB * 16;

  // ======== phase A: staging ========
  for (int f = tid; f < HH * 3 * HH; f += NT) {  // WhhT[k][row] = Whh[row][k]
    int k = f / (3 * HH), row = f - k * (3 * HH);
    s_WhhT[k][row] = Whh[(size_t)row * HH + k];
  }
  for (int f = tid; f < HH * HH; f += NT) {      // W1cT[k][row] = W1[row][DD+k]
    int k = f >> 6, row = f & (HH - 1);
    s_W1cT[k][row] = W1[(size_t)row * (DD + HH) + DD + k];
  }
  if (tid < 3 * HH) s_bhh[tid] = bhh[tid];
  if (tid >= 256 && tid < 256 + HH) s_b1[tid - 256] = b1[tid - 256];
  if (tid >= 320 && tid < 320 + HH) s_W2v[tid - 320] = W2[tid - 320];
  s_avail[t] = (mask[b * NB + t] != 0) ? 1 : 0;
  s_avail[t + NT] = (mask[b * NB + t + NT] != 0) ? 1 : 0;
  s_assignB[t] = 0;
  s_assignB[t + NT] = 0;
  if (tid >= 384 && tid < 384 + DD) {
    int d = tid - 384;
    float m = 0.f;
#pragma unroll
    for (int k = 0; k < 16; k++) m += ws[OFF_PART + ((size_t)b * 16 + k) * DD + d];
    s_mean[d] = m * (1.0f / NB);
  }
  if (tid == 0) s_b2v = b2[0];
  __syncthreads();

  // ======== phase B: ctx = bc + Wc @ mean ========
  if (tid < 4 * HH) {
    int row = tid >> 2, g = tid & 3;
    const float4* wr = (const float4*)(Wc + (size_t)row * DD) + g * 8;
    const float4* m4 = (const float4*)s_mean + g * 8;
    float s = 0.f;
#pragma unroll
    for (int i = 0; i < 8; i++) {
      float4 w = wr[i], m = m4[i];
      s += w.x * m.x + w.y * m.y + w.z * m.z + w.w * m.w;
    }
    s += __shfl_xor(s, 1);
    s += __shfl_xor(s, 2);
    if (g == 0) s_ctx[row] = s + bc[row];
  }
  __syncthreads();

  // ======== phase C: q0 (wave 0) + state zero ========
  if (tid < 64) {
    int r = tid;
    float qs = 0.f;
    for (int k = 0; k < HH; k += 4) {
      float4 cv = *(const float4*)&s_ctx[k];
      qs += s_W1cT[k][r] * cv.x + s_W1cT[k + 1][r] * cv.y +
            s_W1cT[k + 2][r] * cv.z + s_W1cT[k + 3][r] * cv.w;
    }
    s_q[r] = qs + s_b1[r];
    s_h[r] = 0.f;
  } else if (tid < 66) s_key[tid - 64] = 0ull;
  else if (tid < 98) ((unsigned long long*)s_top2)[tid - 66] = 0ull;
  else if (tid == 98) s_cnt = 0;
  __syncthreads();

  float l0, l1;  // logits persist in registers L -> HS

  for (int c = 0; c < MAXC; c++) {
    // ======== L: logits + sel0 scan ========
    {
      unsigned ka, kb;
      tf2x32(0u, 42u, 0u, (unsigned)(2 * c), ka, kb);
      const float4* p0 = P4 + (size_t)t * 16;
      const float4* p1 = P4 + (size_t)(t + NT) * 16;
      l0 = s_b2v;
      l1 = s_b2v;
#pragma unroll
      for (int i = 0; i < 16; i++) {
        float4 pa = p0[i], pb = p1[i];
        float4 qv = *(const float4*)&s_q[i * 4];
        float4 w = *(const float4*)&s_W2v[i * 4];
        l0 += w.x * fmaxf(pa.x + qv.x, 0.f) + w.y * fmaxf(pa.y + qv.y, 0.f) +
              w.z * fmaxf(pa.z + qv.z, 0.f) + w.w * fmaxf(pa.w + qv.w, 0.f);
        l1 += w.x * fmaxf(pb.x + qv.x, 0.f) + w.y * fmaxf(pb.y + qv.y, 0.f) +
              w.z * fmaxf(pb.z + qv.z, 0.f) + w.w * fmaxf(pb.w + qv.w, 0.f);
      }
      unsigned long long key = 0ull;
      if (s_avail[t]) key = packKey(l0 + gumbel_for(ka, kb, (unsigned)(b * NB + t)), t);
      if (s_avail[t + NT]) {
        unsigned long long k2 =
            packKey(l1 + gumbel_for(ka, kb, (unsigned)(b * NB + t + NT)), t + NT);
        if (k2 > key) key = k2;
      }
#pragma unroll
      for (int off = 32; off; off >>= 1) {
        unsigned long long o = __shfl_down(key, off);
        if (o > key) key = o;
      }
      if ((tid & 63) == 0 && key) atomicMax(&s_key[0], key);
    }
    __syncthreads();

    // ======== H0: seed row (own columns) + frontier build ========
    const int seed = decodeKey(s_key[0]);
    bool r0 = false, r1 = false;
    if (seed >= 0) {
      const float* srow = adj + adjb + (size_t)seed * NB;
      float a0v = srow[t], a1v = srow[t + NT];
      r0 = a0v > 0.f;
      r1 = a1v > 0.f;
      if (r0) { int p = atomicAdd(&s_cnt, 1); if (p < 128) s_flist[p] = (short)t; }
      if (r1) { int p = atomicAdd(&s_cnt, 1); if (p < 128) s_flist[p] = (short)(t + NT); }
      r0 |= (t == seed);
      r1 |= (t + NT == seed);
      if (tid == 0) s_avail[seed] = 0;
    }
    // inline gumbels for sel1/sel2 (VALU, overlaps the loads above)
    unsigned k1a, k1b, k2a, k2b;
    tf2x32(0u, 42u, 0u, (unsigned)(2 * c + 1000), k1a, k1b);
    tf2x32(0u, 42u, 0u, (unsigned)(2 * c + 1001), k2a, k2b);
    float g1a = gumbel_for(k1a, k1b, (unsigned)(b * NB + t));
    float g1b = gumbel_for(k1a, k1b, (unsigned)(b * NB + t + NT));
    float g2a = gumbel_for(k2a, k2b, (unsigned)(b * NB + t));
    float g2b = gumbel_for(k2a, k2b, (unsigned)(b * NB + t + NT));
    __syncthreads();

    // ======== HS: hop1 (register-local reach) + sel1 argmax + sel2 top-2 ========
    if (seed >= 0) {
      int fc = min(s_cnt, 128);
      const float* ab = adj + adjb;
      int fi = 0;
      for (; fi + 2 <= fc; fi += 2) {
        int ra = s_flist[fi], rb = s_flist[fi + 1];
        float a0 = ab[(size_t)ra * NB + t], a1 = ab[(size_t)ra * NB + t + NT];
        float c0 = ab[(size_t)rb * NB + t], c1 = ab[(size_t)rb * NB + t + NT];
        r0 |= (a0 > 0.f) | (c0 > 0.f);
        r1 |= (a1 > 0.f) | (c1 > 0.f);
      }
      if (fi < fc) {
        int ra = s_flist[fi];
        r0 |= ab[(size_t)ra * NB + t] > 0.f;
        r1 |= ab[(size_t)ra * NB + t + NT] > 0.f;
      }
    }
    {
      bool c0 = r0 && s_avail[t], c1 = r1 && s_avail[t + NT];
      unsigned long long key1 = 0ull, ta = 0ull, tb = 0ull;
      if (c0) {
        key1 = packKey(l0 + g1a, t);
        ta = packKey(l0 + g2a, t);
      }
      if (c1) {
        unsigned long long k = packKey(l1 + g1b, t + NT);
        if (k > key1) key1 = k;
        unsigned long long k2 = packKey(l1 + g2b, t + NT);
        if (k2 > ta) { tb = ta; ta = k2; } else tb = k2;
      }
#pragma unroll
      for (int off = 32; off; off >>= 1) {
        unsigned long long o = __shfl_down(key1, off);
        if (o > key1) key1 = o;
        unsigned long long o1 = __shfl_down(ta, off);
        unsigned long long o2 = __shfl_down(tb, off);
        unsigned long long lo = ta < o1 ? ta : o1;
        unsigned long long hi2 = tb > o2 ? tb : o2;
        ta = ta > o1 ? ta : o1;
        tb = lo > hi2 ? lo : hi2;
      }
      if ((tid & 63) == 0) {
        if (key1) atomicMax(&s_key[1], key1);
        s_top2[tid >> 6][0] = ta;
        s_top2[tid >> 6][1] = tb;
      }
    }
    __syncthreads();

    // ======== M: winner merge + gi + emb + avail/assign ========
    const int w1 = decodeKey(s_key[1]);
    int w2;
    {
      unsigned long long t1 = 0ull, t2 = 0ull;
#pragma unroll
      for (int i = 0; i < 32; i++) {
        unsigned long long k = ((unsigned long long*)s_top2)[i];
        if (k > t1) { t2 = t1; t1 = k; } else if (k > t2) t2 = k;
      }
      int i1 = decodeKey(t1);
      w2 = (i1 == w1) ? decodeKey(t2) : i1;
    }
    {
      int mc = (seed >= 0) + (w1 >= 0) + (w2 >= 0);
      float invmc = 1.0f / fmaxf((float)mc, 1.0f);
      if (c < MAXC - 1 && tid < 768) {  // gi[c] = bih + Wih @ emb (from x rows directly)
        int row = tid >> 2, g = tid & 3;
        const float4* wr = (const float4*)(Wih + (size_t)row * DD) + g * 8;
        const float4* x0 = (seed >= 0) ? (const float4*)(x + xb + (size_t)seed * DD) + g * 8 : nullptr;
        const float4* x1 = (w1 >= 0) ? (const float4*)(x + xb + (size_t)w1 * DD) + g * 8 : nullptr;
        const float4* x2 = (w2 >= 0) ? (const float4*)(x + xb + (size_t)w2 * DD) + g * 8 : nullptr;
        float s = 0.f;
#pragma unroll
        for (int i = 0; i < 8; i++) {
          float4 w = wr[i];
          float sx = 0.f, sy = 0.f, sz = 0.f, sw = 0.f;
          if (x0) { float4 v = x0[i]; sx += v.x; sy += v.y; sz += v.z; sw += v.w; }
          if (x1) { float4 v = x1[i]; sx += v.x; sy += v.y; sz += v.z; sw += v.w; }
          if (x2) { float4 v = x2[i]; sx += v.x; sy += v.y; sz += v.z; sw += v.w; }
          s += w.x * sx + w.y * sy + w.z * sz + w.w * sw;
        }
        s += __shfl_xor(s, 1);
        s += __shfl_xor(s, 2);
        if (g == 0) s_giAll[c][row] = s * invmc + bih[row];
      }
      if (tid >= 768 && tid < 768 + DD) {  // emb -> out_feat
        int d = tid - 768;
        float acc = 0.f;
        if (seed >= 0) acc += x[xb + (size_t)seed * DD + d];
        if (w1 >= 0) acc += x[xb + (size_t)w1 * DD + d];
        if (w2 >= 0) acc += x[xb + (size_t)w2 * DD + d];
        out_feat[((size_t)b * MAXC + c) * DD + d] = acc * invmc;
      }
      if (tid == 896 && seed >= 0) s_assignB[seed] |= (unsigned char)(1 << c);
      if (tid == 897 && w1 >= 0) { s_assignB[w1] |= (unsigned char)(1 << c); s_avail[w1] = 0; }
      if (tid == 898 && w2 >= 0) { s_assignB[w2] |= (unsigned char)(1 << c); s_avail[w2] = 0; }
    }
    __syncthreads();

    // ======== G: wave-synchronous GRU (wave 0, zero inner barriers) + q ========
    if (c < MAXC - 1) {
      if (tid < 64) {
        const int r = tid;
        float h = s_h[r];
        for (int tt = 0; tt <= c; tt++) {
          float sr = 0.f, sz = 0.f, sn = 0.f;
          for (int k = 0; k < HH; k += 4) {
            float4 hv = *(const float4*)&s_h[k];  // broadcast read
            sr += s_WhhT[k][r] * hv.x + s_WhhT[k + 1][r] * hv.y +
                  s_WhhT[k + 2][r] * hv.z + s_WhhT[k + 3][r] * hv.w;
            sz += s_WhhT[k][HH + r] * hv.x + s_WhhT[k + 1][HH + r] * hv.y +
                  s_WhhT[k + 2][HH + r] * hv.z + s_WhhT[k + 3][HH + r] * hv.w;
            sn += s_WhhT[k][2 * HH + r] * hv.x + s_WhhT[k + 1][2 * HH + r] * hv.y +
                  s_WhhT[k + 2][2 * HH + r] * hv.z + s_WhhT[k + 3][2 * HH + r] * hv.w;
          }
          float rr = 1.f / (1.f + expf(-(s_giAll[tt][r] + sr + s_bhh[r])));
          float zz = 1.f / (1.f + expf(-(s_giAll[tt][HH + r] + sz + s_bhh[HH + r])));
          float nn = tanhf(s_giAll[tt][2 * HH + r] + rr * (sn + s_bhh[2 * HH + r]));
          h = (1.f - zz) * nn + zz * h;
          s_h[r] = h;  // wave-sync: visible to all lanes next iteration
        }
        float qs = 0.f;
        for (int k = 0; k < HH; k += 4) {
          float4 hv = *(const float4*)&s_h[k];
          qs += s_W1cT[k][r] * hv.x + s_W1cT[k + 1][r] * hv.y +
                s_W1cT[k + 2][r] * hv.z + s_W1cT[k + 3][r] * hv.w;
        }
        s_q[r] = qs + s_b1[r];
      } else if (tid < 66) s_key[tid - 64] = 0ull;
      else if (tid < 98) ((unsigned long long*)s_top2)[tid - 66] = 0ull;
      else if (tid == 98) s_cnt = 0;
      __syncthreads();
    }
  }  // clusters

  // ======== final coalesced writes ========
#pragma unroll
  for (int rr = 0; rr < 2; rr++) {
    int n = t + rr * NT;
    unsigned bits = s_assignB[n];
    size_t basei = ((size_t)(b * NB + n)) * MAXC;
#pragma unroll
    for (int cc = 0; cc < MAXC; cc++)
      out_assign[basei + cc] = (float)((bits >> cc) & 1u);
  }
  for (int i = tid; i < MAXC * MAXC; i += NT) {
    out_adjm[(size_t)b * MAXC * MAXC + i] = ((i / MAXC) == (i % MAXC)) ? 0.f : 1.f;
  }
}

extern "C" void kernel_launch(void* const* d_in, const int* in_sizes, int n_in,
                              void* d_out, int out_size, void* d_ws, size_t ws_size,
                              hipStream_t stream) {
  const float* x   = (const float*)d_in[0];
  const float* adj = (const float*)d_in[1];
  const int*   mask= (const int*)d_in[2];
  const float* W1  = (const float*)d_in[3];
  const float* b1  = (const float*)d_in[4];
  const float* W2  = (const float*)d_in[5];
  const float* b2  = (const float*)d_in[6];
  const float* Wc  = (const float*)d_in[7];
  const float* bc  = (const float*)d_in[8];
  const float* Wih = (const float*)d_in[9];
  const float* Whh = (const float*)d_in[10];
  const float* bih = (const float*)d_in[11];
  const float* bhh = (const float*)d_in[12];

  float* ws = (float*)d_ws;
  float* out = (float*)d_out;
  float* out_feat = out;                                     // [B,5,D]
  float* out_adjm = out + (size_t)BB * MAXC * DD;            // [B,5,5]
  float* out_assign = out_adjm + (size_t)BB * MAXC * MAXC;   // [B,N,5]

  hipLaunchKernelGGL(gvp_prep, dim3(384), dim3(1024), 0, stream, x, W1, ws);
  hipLaunchKernelGGL(gvp_main, dim3(BB), dim3(NT), 0, stream,
                     x, adj, mask, W1, b1, W2, b2, Wc, bc, Wih, Whh, bih, bhh, ws,
                     out_feat, out_adjm, out_assign);
}

// Round 11
// 267.811 us; speedup vs baseline: 1.2205x; 1.2205x over previous
//
#include <hip/hip_runtime.h>
#include <cfloat>
#include <cmath>

#define NB 2048
#define BB 16
#define DD 128
#define HH 64
#define MAXC 5
#define NT 1024

#define OFF_P 0                          // [BB*NB][HH] 8 MB
#define OFF_PART (OFF_P + BB * NB * HH)  // [BB][16][DD]

// ---------------- Threefry-2x32 (JAX-exact) ----------------
__device__ __forceinline__ unsigned rotl32(unsigned v, int d) {
  return (v << d) | (v >> (32 - d));
}

__device__ __forceinline__ void tf2x32(unsigned k0, unsigned k1, unsigned x0, unsigned x1,
                                       unsigned& o0, unsigned& o1) {
  unsigned ks2 = k0 ^ k1 ^ 0x1BD11BDAu;
  x0 += k0; x1 += k1;
#define RND(r) { x0 += x1; x1 = rotl32(x1, r); x1 ^= x0; }
  RND(13) RND(15) RND(26) RND(6)   x0 += k1;  x1 += ks2 + 1u;
  RND(17) RND(29) RND(16) RND(24)  x0 += ks2; x1 += k0 + 2u;
  RND(13) RND(15) RND(26) RND(6)   x0 += k0;  x1 += k1 + 3u;
  RND(17) RND(29) RND(16) RND(24)  x0 += k1;  x1 += ks2 + 4u;
  RND(13) RND(15) RND(26) RND(6)   x0 += ks2; x1 += k0 + 5u;
#undef RND
  o0 = x0; o1 = x1;
}

__device__ __forceinline__ float gumbel_for(unsigned k0, unsigned k1, unsigned idx) {
  unsigned o0, o1;
  tf2x32(k0, k1, 0u, idx, o0, o1);
  unsigned bits = o0 ^ o1;
  float u = __uint_as_float((bits >> 9) | 0x3f800000u) - 1.0f;
  float uu = u + 1e-8f;
  return -logf(-logf(uu) + 1e-8f);
}

__device__ __forceinline__ unsigned long long packKey(float y, int n) {
  unsigned u = __float_as_uint(y);
  u = (u & 0x80000000u) ? ~u : (u | 0x80000000u);
  return ((unsigned long long)u << 32) | (unsigned)(~(unsigned)n);
}
__device__ __forceinline__ int decodeKey(unsigned long long k) {
  return k ? (int)(~(unsigned)k) : -1;
}

// ---------------- prep: P-GEMM + mean partials ----------------
__global__ __launch_bounds__(1024) void gvp_prep(
    const float* __restrict__ x, const float* __restrict__ W1, float* __restrict__ ws) {
  __shared__ __align__(16) float s_W1[HH][DD + 4];
  __shared__ float sp[8][DD];
  const int bid = blockIdx.x, tid = threadIdx.x;
  float* P = ws + OFF_P;
  float* partial = ws + OFF_PART;

  if (bid < 128) {
    for (int i = tid; i < HH * (DD / 4); i += 1024) {
      int r = i >> 5, q = i & 31;
      *(float4*)&s_W1[r][q * 4] = *(const float4*)(W1 + (size_t)r * (DD + HH) + q * 4);
    }
    __syncthreads();
    const int jg = tid & 15, ng = tid >> 4;
    const int j0 = jg * 4;
    const size_t n0 = (size_t)bid * 256 + ng * 4;
    const float4* x4 = (const float4*)x;
    float acc[4][4];
#pragma unroll
    for (int i = 0; i < 4; i++)
#pragma unroll
      for (int q = 0; q < 4; q++) acc[i][q] = 0.f;
    for (int kq = 0; kq < 32; kq++) {
      float4 xv[4], wv[4];
#pragma unroll
      for (int i = 0; i < 4; i++) xv[i] = x4[(n0 + i) * 32 + kq];
#pragma unroll
      for (int q = 0; q < 4; q++) wv[q] = *(const float4*)&s_W1[j0 + q][kq * 4];
#pragma unroll
      for (int i = 0; i < 4; i++)
#pragma unroll
        for (int q = 0; q < 4; q++)
          acc[i][q] += xv[i].x * wv[q].x + xv[i].y * wv[q].y +
                       xv[i].z * wv[q].z + xv[i].w * wv[q].w;
    }
#pragma unroll
    for (int i = 0; i < 4; i++)
#pragma unroll
      for (int q = 0; q < 4; q++)
        P[(n0 + i) * HH + j0 + q] = acc[i][q];
  } else {
    const int bm = bid - 128;
    const int b = bm >> 4, chunk = bm & 15;
    const int d = tid & (DD - 1), part = tid >> 7;
    float acc = 0.f;
    const int base = chunk * 128 + part;
#pragma unroll
    for (int k = 0; k < 16; k++)
      acc += x[((size_t)b * NB + base + k * 8) * DD + d];
    sp[part][d] = acc;
    __syncthreads();
    if (tid < DD) {
      float m = 0.f;
#pragma unroll
      for (int p = 0; p < 8; p++) m += sp[p][tid];
      partial[((size_t)b * 16 + chunk) * DD + tid] = m;
    }
  }
}

// ---------------- main: 1 block (1024 thr) per batch, ~33 phases ----------------
__global__ __launch_bounds__(NT, 4) void gvp_main(
    const float* __restrict__ x, const float* __restrict__ adj, const int* __restrict__ mask,
    const float* __restrict__ W1, const float* __restrict__ b1,
    const float* __restrict__ W2, const float* __restrict__ b2,
    const float* __restrict__ Wc, const float* __restrict__ bc,
    const float* __restrict__ Wih, const float* __restrict__ Whh,
    const float* __restrict__ bih, const float* __restrict__ bhh,
    const float* __restrict__ ws,
    float* __restrict__ out_feat, float* __restrict__ out_adjm, float* __restrict__ out_assign) {
  const int b = blockIdx.x;
  const int tid = threadIdx.x;
  const int t = tid;

  __shared__ float s_WhhT[HH][3 * HH + 1];  // [k][gate*64+row], stride 193: r/w ~2 lanes/bank
  __shared__ float s_W1cT[HH][HH + 1];      // [k][row], stride 65
  __shared__ __align__(16) float s_logits[NB];
  __shared__ unsigned char s_avail[NB], s_reach[NB], s_assignB[NB];
  __shared__ short s_flist[128];
  __shared__ int s_cnt;
  __shared__ unsigned long long s_key[2];
  __shared__ unsigned long long s_top2[16][2];
  __shared__ __align__(16) float s_giAll[MAXC][3 * HH];
  __shared__ __align__(16) float s_h[HH], s_q[HH], s_ctx[HH];
  __shared__ __align__(16) float s_mean[DD];
  __shared__ float s_bhh[3 * HH], s_b1[HH], s_W2v[HH];
  __shared__ float s_b2v;

  const size_t adjb = (size_t)b * NB * NB;
  const size_t xb = (size_t)b * NB * DD;
  const float4* adj4 = (const float4*)(adj + adjb);
  const float4* P4 = (const float4*)(ws + OFF_P) + (size_t)b * NB * 16;

  // ======== A: staging ========
  for (int f = tid; f < HH * 3 * HH; f += NT) {  // coalesced global, conflict-free LDS (stride 193)
    int k = f & 63, row = f >> 6;
    s_WhhT[k][row] = Whh[(size_t)row * HH + k];
  }
  for (int f = tid; f < HH * HH; f += NT) {
    int k = f & 63, row = f >> 6;
    s_W1cT[k][row] = W1[(size_t)row * (DD + HH) + DD + k];
  }
  if (tid < 3 * HH) s_bhh[tid] = bhh[tid];
  if (tid >= 256 && tid < 256 + HH) s_b1[tid - 256] = b1[tid - 256];
  if (tid >= 320 && tid < 320 + HH) s_W2v[tid - 320] = W2[tid - 320];
  s_avail[t] = (mask[b * NB + t] != 0) ? 1 : 0;
  s_avail[t + NT] = (mask[b * NB + t + NT] != 0) ? 1 : 0;
  s_assignB[t] = 0;
  s_assignB[t + NT] = 0;
  if (tid >= 384 && tid < 384 + DD) {
    int d = tid - 384;
    float m = 0.f;
#pragma unroll
    for (int k = 0; k < 16; k++) m += ws[OFF_PART + ((size_t)b * 16 + k) * DD + d];
    s_mean[d] = m * (1.0f / NB);
  }
  if (tid == 0) s_b2v = b2[0];
  __syncthreads();

  // ======== B: ctx = bc + Wc @ mean ========
  if (tid < 4 * HH) {
    int row = tid >> 2, g = tid & 3;
    const float4* wr = (const float4*)(Wc + (size_t)row * DD) + g * 8;
    const float4* m4 = (const float4*)s_mean + g * 8;
    float s = 0.f;
#pragma unroll
    for (int i = 0; i < 8; i++) {
      float4 w = wr[i], m = m4[i];
      s += w.x * m.x + w.y * m.y + w.z * m.z + w.w * m.w;
    }
    s += __shfl_xor(s, 1);
    s += __shfl_xor(s, 2);
    if (g == 0) s_ctx[row] = s + bc[row];
  }
  __syncthreads();

  // ======== C: q0 (wave 0) + state zero ========
  if (tid < 64) {
    const int r = tid;
    float qs = 0.f;
    for (int k = 0; k < HH; k += 4) {
      float4 cv = *(const float4*)&s_ctx[k];
      qs += s_W1cT[k][r] * cv.x + s_W1cT[k + 1][r] * cv.y +
            s_W1cT[k + 2][r] * cv.z + s_W1cT[k + 3][r] * cv.w;
    }
    s_q[r] = qs + s_b1[r];
    s_h[r] = 0.f;
  } else if (tid < 66) s_key[tid - 64] = 0ull;
  else if (tid < 98) ((unsigned long long*)s_top2)[tid - 66] = 0ull;
  else if (tid == 98) s_cnt = 0;
  __syncthreads();

  for (int c = 0; c < MAXC; c++) {
    // ======== L: logits (-> LDS) + sel0 scan (in-phase gumbel) ========
    {
      unsigned ka, kb;
      tf2x32(0u, 42u, 0u, (unsigned)(2 * c), ka, kb);
      const float4* p0 = P4 + (size_t)t * 16;
      const float4* p1 = P4 + (size_t)(t + NT) * 16;
      float l0 = s_b2v, l1 = s_b2v;
#pragma unroll
      for (int i = 0; i < 16; i++) {
        float4 pa = p0[i], pb = p1[i];
        float4 qv = *(const float4*)&s_q[i * 4];
        float4 w = *(const float4*)&s_W2v[i * 4];
        l0 += w.x * fmaxf(pa.x + qv.x, 0.f) + w.y * fmaxf(pa.y + qv.y, 0.f) +
              w.z * fmaxf(pa.z + qv.z, 0.f) + w.w * fmaxf(pa.w + qv.w, 0.f);
        l1 += w.x * fmaxf(pb.x + qv.x, 0.f) + w.y * fmaxf(pb.y + qv.y, 0.f) +
              w.z * fmaxf(pb.z + qv.z, 0.f) + w.w * fmaxf(pb.w + qv.w, 0.f);
      }
      s_logits[t] = l0;
      s_logits[t + NT] = l1;
      unsigned long long key = 0ull;
      if (s_avail[t]) key = packKey(l0 + gumbel_for(ka, kb, (unsigned)(b * NB + t)), t);
      if (s_avail[t + NT]) {
        unsigned long long k2 =
            packKey(l1 + gumbel_for(ka, kb, (unsigned)(b * NB + t + NT)), t + NT);
        if (k2 > key) key = k2;
      }
#pragma unroll
      for (int off = 32; off; off >>= 1) {
        unsigned long long o = __shfl_down(key, off);
        if (o > key) key = o;
      }
      if ((tid & 63) == 0 && key) atomicMax(&s_key[0], key);
    }
    __syncthreads();

    // ======== H0: seed row -> s_reach + frontier ========
    const int seed = decodeKey(s_key[0]);
    if (tid < 512) {
      if (seed >= 0) {
        float4 a = adj4[(size_t)seed * 512 + tid];
        int m = tid << 2;
        unsigned f0 = a.x > 0.f, f1 = a.y > 0.f, f2 = a.z > 0.f, f3 = a.w > 0.f;
        unsigned r = f0 | (f1 << 8) | (f2 << 16) | (f3 << 24);
        if ((seed >> 2) == tid) r |= 1u << ((seed & 3) * 8);
        ((unsigned*)s_reach)[tid] = r;
        if (f0 && m != seed)     { int p = atomicAdd(&s_cnt, 1); if (p < 128) s_flist[p] = (short)m; }
        if (f1 && m + 1 != seed) { int p = atomicAdd(&s_cnt, 1); if (p < 128) s_flist[p] = (short)(m + 1); }
        if (f2 && m + 2 != seed) { int p = atomicAdd(&s_cnt, 1); if (p < 128) s_flist[p] = (short)(m + 2); }
        if (f3 && m + 3 != seed) { int p = atomicAdd(&s_cnt, 1); if (p < 128) s_flist[p] = (short)(m + 3); }
      } else {
        ((unsigned*)s_reach)[tid] = 0u;
      }
    }
    if (tid == 512 && seed >= 0) s_avail[seed] = 0;
    __syncthreads();

    // ======== H1: hop1 — OR frontier rows into s_reach (R4-proven form) ========
    if (seed >= 0) {
      int cnt = min(s_cnt, 128);
      int m4 = tid & 511, rg = tid >> 9;
      bool a0 = false, a1 = false, a2 = false, a3 = false;
#pragma unroll
      for (int k = 0; k < 20; k++) {
        int li = rg + 2 * k;
        if (li < cnt) {
          int n = s_flist[li];
          float4 a = adj4[(size_t)n * 512 + m4];
          a0 |= a.x > 0.f; a1 |= a.y > 0.f; a2 |= a.z > 0.f; a3 |= a.w > 0.f;
        }
      }
      for (int li = rg + 40; li < cnt; li += 2) {
        int n = s_flist[li];
        float4 a = adj4[(size_t)n * 512 + m4];
        a0 |= a.x > 0.f; a1 |= a.y > 0.f; a2 |= a.z > 0.f; a3 |= a.w > 0.f;
      }
      int m = m4 << 2;
      if (a0) s_reach[m] = 1;
      if (a1) s_reach[m + 1] = 1;
      if (a2) s_reach[m + 2] = 1;
      if (a3) s_reach[m + 3] = 1;
    }
    __syncthreads();

    // ======== S12: fused sel1 argmax + sel2 top-2 (logits from LDS, in-phase gumbel) ====
    {
      unsigned k1a, k1b, k2a, k2b;
      tf2x32(0u, 42u, 0u, (unsigned)(2 * c + 1000), k1a, k1b);
      tf2x32(0u, 42u, 0u, (unsigned)(2 * c + 1001), k2a, k2b);
      bool c0 = s_avail[t] && s_reach[t];
      bool c1 = s_avail[t + NT] && s_reach[t + NT];
      unsigned long long key1 = 0ull, ta = 0ull, tb = 0ull;
      if (c0) {
        float lg = s_logits[t];
        key1 = packKey(lg + gumbel_for(k1a, k1b, (unsigned)(b * NB + t)), t);
        ta = packKey(lg + gumbel_for(k2a, k2b, (unsigned)(b * NB + t)), t);
      }
      if (c1) {
        float lg = s_logits[t + NT];
        unsigned long long k = packKey(lg + gumbel_for(k1a, k1b, (unsigned)(b * NB + t + NT)), t + NT);
        if (k > key1) key1 = k;
        unsigned long long k2 = packKey(lg + gumbel_for(k2a, k2b, (unsigned)(b * NB + t + NT)), t + NT);
        if (k2 > ta) { tb = ta; ta = k2; } else tb = k2;
      }
#pragma unroll
      for (int off = 32; off; off >>= 1) {
        unsigned long long o = __shfl_down(key1, off);
        if (o > key1) key1 = o;
        unsigned long long o1 = __shfl_down(ta, off);
        unsigned long long o2 = __shfl_down(tb, off);
        unsigned long long lo = ta < o1 ? ta : o1;
        unsigned long long hi2 = tb > o2 ? tb : o2;
        ta = ta > o1 ? ta : o1;
        tb = lo > hi2 ? lo : hi2;
      }
      if ((tid & 63) == 0) {
        if (key1) atomicMax(&s_key[1], key1);
        s_top2[tid >> 6][0] = ta;
        s_top2[tid >> 6][1] = tb;
      }
    }
    __syncthreads();

    // ======== M: winner merge + gi (c<4) + emb + avail/assign ========
    {
      const int w1 = decodeKey(s_key[1]);
      int w2;
      {
        unsigned long long t1 = 0ull, t2 = 0ull;
#pragma unroll
        for (int i = 0; i < 32; i++) {
          unsigned long long k = ((unsigned long long*)s_top2)[i];
          if (k > t1) { t2 = t1; t1 = k; } else if (k > t2) t2 = k;
        }
        int i1 = decodeKey(t1);
        w2 = (i1 == w1) ? decodeKey(t2) : i1;
      }
      int mc = (seed >= 0) + (w1 >= 0) + (w2 >= 0);
      float invmc = 1.0f / fmaxf((float)mc, 1.0f);
      if (c < MAXC - 1 && tid < 768) {  // gi[c] = bih + Wih @ emb (from x rows)
        int row = tid >> 2, g = tid & 3;
        const float4* wr = (const float4*)(Wih + (size_t)row * DD) + g * 8;
        const float4* x0 = (seed >= 0) ? (const float4*)(x + xb + (size_t)seed * DD) + g * 8 : nullptr;
        const float4* x1 = (w1 >= 0) ? (const float4*)(x + xb + (size_t)w1 * DD) + g * 8 : nullptr;
        const float4* x2 = (w2 >= 0) ? (const float4*)(x + xb + (size_t)w2 * DD) + g * 8 : nullptr;
        float s = 0.f;
#pragma unroll
        for (int i = 0; i < 8; i++) {
          float4 w = wr[i];
          float sx = 0.f, sy = 0.f, sz = 0.f, sw = 0.f;
          if (x0) { float4 v = x0[i]; sx += v.x; sy += v.y; sz += v.z; sw += v.w; }
          if (x1) { float4 v = x1[i]; sx += v.x; sy += v.y; sz += v.z; sw += v.w; }
          if (x2) { float4 v = x2[i]; sx += v.x; sy += v.y; sz += v.z; sw += v.w; }
          s += w.x * sx + w.y * sy + w.z * sz + w.w * sw;
        }
        s += __shfl_xor(s, 1);
        s += __shfl_xor(s, 2);
        if (g == 0) s_giAll[c][row] = s * invmc + bih[row];
      }
      if (tid >= 768 && tid < 768 + DD) {  // emb -> out_feat
        int d = tid - 768;
        float acc = 0.f;
        if (seed >= 0) acc += x[xb + (size_t)seed * DD + d];
        if (w1 >= 0) acc += x[xb + (size_t)w1 * DD + d];
        if (w2 >= 0) acc += x[xb + (size_t)w2 * DD + d];
        out_feat[((size_t)b * MAXC + c) * DD + d] = acc * invmc;
      }
      if (tid == 896 && seed >= 0) s_assignB[seed] |= (unsigned char)(1 << c);
      if (tid == 897 && w1 >= 0) { s_assignB[w1] |= (unsigned char)(1 << c); s_avail[w1] = 0; }
      if (tid == 898 && w2 >= 0) { s_assignB[w2] |= (unsigned char)(1 << c); s_avail[w2] = 0; }
    }
    __syncthreads();

    // ======== G (c<4): wave-sync GRU (wave 0, zero inner barriers) + q; zero keys ========
    if (c < MAXC - 1) {
      if (tid < 64) {
        const int r = tid;
        float h = s_h[r];
        for (int tt = 0; tt <= c; tt++) {
          float sr = 0.f, sz = 0.f, sn = 0.f;
          for (int k = 0; k < HH; k += 4) {
            float4 hv = *(const float4*)&s_h[k];  // broadcast
            sr += s_WhhT[k][r] * hv.x + s_WhhT[k + 1][r] * hv.y +
                  s_WhhT[k + 2][r] * hv.z + s_WhhT[k + 3][r] * hv.w;
            sz += s_WhhT[k][HH + r] * hv.x + s_WhhT[k + 1][HH + r] * hv.y +
                  s_WhhT[k + 2][HH + r] * hv.z + s_WhhT[k + 3][HH + r] * hv.w;
            sn += s_WhhT[k][2 * HH + r] * hv.x + s_WhhT[k + 1][2 * HH + r] * hv.y +
                  s_WhhT[k + 2][2 * HH + r] * hv.z + s_WhhT[k + 3][2 * HH + r] * hv.w;
          }
          float rr = 1.f / (1.f + expf(-(s_giAll[tt][r] + sr + s_bhh[r])));
          float zz = 1.f / (1.f + expf(-(s_giAll[tt][HH + r] + sz + s_bhh[HH + r])));
          float nn = tanhf(s_giAll[tt][2 * HH + r] + rr * (sn + s_bhh[2 * HH + r]));
          h = (1.f - zz) * nn + zz * h;
          s_h[r] = h;  // wave-synchronous: visible next iteration
        }
        float qs = 0.f;
        for (int k = 0; k < HH; k += 4) {
          float4 hv = *(const float4*)&s_h[k];
          qs += s_W1cT[k][r] * hv.x + s_W1cT[k + 1][r] * hv.y +
                s_W1cT[k + 2][r] * hv.z + s_W1cT[k + 3][r] * hv.w;
        }
        s_q[r] = qs + s_b1[r];
      } else if (tid < 66) s_key[tid - 64] = 0ull;
      else if (tid < 98) ((unsigned long long*)s_top2)[tid - 66] = 0ull;
      else if (tid == 98) s_cnt = 0;
      __syncthreads();
    }
  }  // clusters

  // ======== final coalesced writes ========
  __syncthreads();
#pragma unroll
  for (int rr = 0; rr < 2; rr++) {
    int n = t + rr * NT;
    unsigned bits = s_assignB[n];
    size_t basei = ((size_t)(b * NB + n)) * MAXC;
#pragma unroll
    for (int cc = 0; cc < MAXC; cc++)
      out_assign[basei + cc] = (float)((bits >> cc) & 1u);
  }
  for (int i = tid; i < MAXC * MAXC; i += NT)
    out_adjm[(size_t)b * MAXC * MAXC + i] = ((i / MAXC) == (i % MAXC)) ? 0.f : 1.f;
}

extern "C" void kernel_launch(void* const* d_in, const int* in_sizes, int n_in,
                              void* d_out, int out_size, void* d_ws, size_t ws_size,
                              hipStream_t stream) {
  const float* x   = (const float*)d_in[0];
  const float* adj = (const float*)d_in[1];
  const int*   mask= (const int*)d_in[2];
  const float* W1  = (const float*)d_in[3];
  const float* b1  = (const float*)d_in[4];
  const float* W2  = (const float*)d_in[5];
  const float* b2  = (const float*)d_in[6];
  const float* Wc  = (const float*)d_in[7];
  const float* bc  = (const float*)d_in[8];
  const float* Wih = (const float*)d_in[9];
  const float* Whh = (const float*)d_in[10];
  const float* bih = (const float*)d_in[11];
  const float* bhh = (const float*)d_in[12];

  float* ws = (float*)d_ws;
  float* out = (float*)d_out;
  float* out_feat = out;                                     // [B,5,D]
  float* out_adjm = out + (size_t)BB * MAXC * DD;            // [B,5,5]
  float* out_assign = out_adjm + (size_t)BB * MAXC * MAXC;   // [B,N,5]

  hipLaunchKernelGGL(gvp_prep, dim3(384), dim3(1024), 0, stream, x, W1, ws);
  hipLaunchKernelGGL(gvp_main, dim3(BB), dim3(NT), 0, stream,
                     x, adj, mask, W1, b1, W2, b2, Wc, bc, Wih, Whh, bih, bhh, ws,
                     out_feat, out_adjm, out_assign);
}

// Round 12
// 200.723 us; speedup vs baseline: 1.6284x; 1.3342x over previous
//
#include <hip/hip_runtime.h>
#include <cfloat>
#include <cmath>

#define NB 2048
#define BB 16
#define DD 128
#define HH 64
#define MAXC 5
#define NSEL (MAXC * CSMAX)
#define CSMAX 3
#define NT 1024
#define REP 8   // independent replicas per batch (identical work/output; DPM-load experiment)

// ---------------- Threefry-2x32 (JAX-exact) ----------------
__device__ __forceinline__ unsigned rotl32(unsigned v, int d) {
  return (v << d) | (v >> (32 - d));
}

__device__ __forceinline__ void tf2x32(unsigned k0, unsigned k1, unsigned x0, unsigned x1,
                                       unsigned& o0, unsigned& o1) {
  unsigned ks2 = k0 ^ k1 ^ 0x1BD11BDAu;
  x0 += k0; x1 += k1;
#define RND(r) { x0 += x1; x1 = rotl32(x1, r); x1 ^= x0; }
  RND(13) RND(15) RND(26) RND(6)   x0 += k1;  x1 += ks2 + 1u;
  RND(17) RND(29) RND(16) RND(24)  x0 += ks2; x1 += k0 + 2u;
  RND(13) RND(15) RND(26) RND(6)   x0 += k0;  x1 += k1 + 3u;
  RND(17) RND(29) RND(16) RND(24)  x0 += k1;  x1 += ks2 + 4u;
  RND(13) RND(15) RND(26) RND(6)   x0 += ks2; x1 += k0 + 5u;
#undef RND
  o0 = x0; o1 = x1;
}

__device__ __forceinline__ float gumbel_for(unsigned k0, unsigned k1, unsigned idx) {
  unsigned o0, o1;
  tf2x32(k0, k1, 0u, idx, o0, o1);
  unsigned bits = o0 ^ o1;
  float u = __uint_as_float((bits >> 9) | 0x3f800000u) - 1.0f;
  float uu = u + 1e-8f;
  return -logf(-logf(uu) + 1e-8f);
}

// ---------------- Fused prep: P-GEMM tiles + mean partials + gumbel ----------------
__global__ __launch_bounds__(NT) void gvp_prep(
    const float* __restrict__ x, const float* __restrict__ W1,
    float* __restrict__ P, float* __restrict__ partial, float* __restrict__ gumb) {
  __shared__ __align__(16) float s_W1[HH][DD + 4];
  __shared__ float sp[8][DD];
  const int bid = blockIdx.x, tid = threadIdx.x;

  if (bid < 128) {
    for (int i = tid; i < HH * (DD / 4); i += NT) {
      int r = i >> 5, q = i & 31;
      *(float4*)&s_W1[r][q * 4] = *(const float4*)(W1 + (size_t)r * (DD + HH) + q * 4);
    }
    __syncthreads();
    const int jg = tid & 15, ng = tid >> 4;
    const int j0 = jg * 4;
    const size_t n0 = (size_t)bid * 256 + ng * 4;
    const float4* x4 = (const float4*)x;
    float acc[4][4];
#pragma unroll
    for (int i = 0; i < 4; i++)
#pragma unroll
      for (int q = 0; q < 4; q++) acc[i][q] = 0.f;
    for (int kq = 0; kq < 32; kq++) {
      float4 xv[4], wv[4];
#pragma unroll
      for (int i = 0; i < 4; i++) xv[i] = x4[(n0 + i) * 32 + kq];
#pragma unroll
      for (int q = 0; q < 4; q++) wv[q] = *(const float4*)&s_W1[j0 + q][kq * 4];
#pragma unroll
      for (int i = 0; i < 4; i++)
#pragma unroll
        for (int q = 0; q < 4; q++)
          acc[i][q] += xv[i].x * wv[q].x + xv[i].y * wv[q].y +
                       xv[i].z * wv[q].z + xv[i].w * wv[q].w;
    }
#pragma unroll
    for (int i = 0; i < 4; i++)
#pragma unroll
      for (int q = 0; q < 4; q++)
        P[(n0 + i) * HH + j0 + q] = acc[i][q];
  } else if (bid < 384) {
    const int bm = bid - 128;
    const int b = bm >> 4, chunk = bm & 15;
    const int d = tid & (DD - 1), part = tid >> 7;
    float acc = 0.f;
    const int base = chunk * 128 + part;
#pragma unroll
    for (int k = 0; k < 16; k++)
      acc += x[((size_t)b * NB + base + k * 8) * DD + d];
    sp[part][d] = acc;
    __syncthreads();
    if (tid < DD) {
      float m = 0.f;
#pragma unroll
      for (int p = 0; p < 8; p++) m += sp[p][tid];
      partial[((size_t)b * 16 + chunk) * DD + tid] = m;
    }
  } else {
    const int bg = bid - 384;
    const int base = (bg * NT + tid) * 4;
#pragma unroll
    for (int i = 0; i < 4; i++) {
      int idx = base + i;
      int sel = idx >> 15;
      int rem = idx & 32767;
      int c = sel / 3, s = sel - 3 * c;
      unsigned data = (s == 0) ? (unsigned)(2 * c) : (unsigned)(2 * c + 1000 + (s - 1));
      unsigned k0, k1;
      tf2x32(0u, 42u, 0u, data, k0, k1);
      gumb[idx] = gumbel_for(k0, k1, (unsigned)rem);
    }
  }
}

// ---------------- Main: REP independent replicas per batch ----------------
__global__ __launch_bounds__(NT, 4) void gvp_main(
    const float* __restrict__ x, const float* __restrict__ adj, const int* __restrict__ mask,
    const float* __restrict__ W1, const float* __restrict__ b1,
    const float* __restrict__ W2, const float* __restrict__ b2,
    const float* __restrict__ Wc, const float* __restrict__ bc,
    const float* __restrict__ Wih, const float* __restrict__ Whh,
    const float* __restrict__ bih, const float* __restrict__ bhh,
    const float* __restrict__ P, const float* __restrict__ partial,
    const float* __restrict__ gumb,
    float* __restrict__ out_feat, float* __restrict__ out_adjm, float* __restrict__ out_assign) {
  const int b = blockIdx.x & 15;  // replica = blockIdx.x >> 4 (computes identical result)
  const int tid = threadIdx.x;

  __shared__ __align__(16) float s_logits[NB];
  __shared__ __align__(16) float s_gumb[2][NB];
  __shared__ unsigned char s_avail[NB], s_reach[NB], s_assignB[NB];
  __shared__ short s_list[128];
  __shared__ int s_cnt;
  __shared__ unsigned long long s_key[CSMAX];
  __shared__ __align__(16) float s_ctx[HH], s_q[HH];
  __shared__ __align__(16) float s_h[2][HH];
  __shared__ __align__(16) float s_hist[MAXC][DD];
  __shared__ __align__(16) float s_giAll[MAXC][3 * HH];
  __shared__ __align__(16) float s_Whh[3 * HH][HH + 4];
  __shared__ __align__(16) float s_W1c[HH][HH + 4];
  __shared__ __align__(16) float s_W2[HH];
  __shared__ float s_bhh[3 * HH], s_b1[HH];
  __shared__ __align__(16) float s_mean[DD];
  __shared__ float s_b2v;

  const size_t xb = (size_t)b * NB * DD;
  const float4* adj4 = (const float4*)(adj + (size_t)b * NB * NB);
  const float4* P4 = (const float4*)(P + (size_t)b * NB * HH);

  auto scanReduce = [&](float bv, int bi, int slot) {
#pragma unroll
    for (int off = 32; off; off >>= 1) {
      float ov = __shfl_down(bv, off);
      int oi = __shfl_down(bi, off);
      if (ov > bv || (ov == bv && oi < bi)) { bv = ov; bi = oi; }
    }
    if ((tid & 63) == 0 && bi < NB) {
      unsigned u = __float_as_uint(bv);
      u = (u & 0x80000000u) ? ~u : (u | 0x80000000u);
      unsigned long long key = ((unsigned long long)u << 32) | (unsigned)(~bi);
      atomicMax(&s_key[slot], key);
    }
  };
  auto decodeIdx = [](unsigned long long k) -> int {
    return k ? (int)(unsigned)(~(unsigned)k) : -1;
  };

  // ---- one-time staging ----
  for (int i = tid; i < 3 * HH * (HH / 4); i += NT) {
    int r = i >> 4, q = i & 15;
    *(float4*)&s_Whh[r][q * 4] = *(const float4*)(Whh + (size_t)r * HH + q * 4);
  }
  {
    int r = tid >> 4, q = tid & 15;
    *(float4*)&s_W1c[r][q * 4] = *(const float4*)(W1 + (size_t)r * (DD + HH) + DD + q * 4);
  }
  if (tid < 3 * HH) s_bhh[tid] = bhh[tid];
  if (tid < HH) { s_W2[tid] = W2[tid]; s_b1[tid] = b1[tid]; s_h[0][tid] = 0.f; }
  if (tid == 0) s_b2v = b2[0];
#pragma unroll
  for (int r = 0; r < 2; r++) {
    int n = tid + r * NT;
    s_avail[n] = (mask[b * NB + n] != 0) ? 1 : 0;
    s_assignB[n] = 0;
  }
  if (tid < DD) {
    float m = 0.f;
#pragma unroll
    for (int k = 0; k < 16; k++) m += partial[((size_t)b * 16 + k) * DD + tid];
    s_mean[tid] = m * (1.0f / NB);
  }
  __syncthreads();
  if (tid < 4 * HH) {  // ctx = bc + Wc @ mean
    int row = tid >> 2, g = tid & 3;
    const float4* wr = (const float4*)(Wc + (size_t)row * DD) + g * 8;
    const float4* m4 = (const float4*)s_mean + g * 8;
    float s = 0.f;
#pragma unroll
    for (int i = 0; i < 8; i++) {
      float4 w = wr[i], m = m4[i];
      s += w.x * m.x + w.y * m.y + w.z * m.z + w.w * m.w;
    }
    s += __shfl_xor(s, 1);
    s += __shfl_xor(s, 2);
    if (g == 0) s_ctx[row] = s + bc[row];
  }
  __syncthreads();

  int hp = 0;  // GRU h parity (uniform across threads)

  for (int c = 0; c < MAXC; c++) {
    // ======== TOP: gumbel stage + q matvec + state reset ========
    const float* g0p = gumb + ((size_t)(c * 3) * BB + b) * NB;
    const float4* g12 = (const float4*)(gumb + ((size_t)(c * 3 + 1 + (tid >> 9)) * BB + b) * NB);
    float4 gst = g12[tid & 511];
    const int n0 = tid, n1 = tid + NT;
    float gs0 = g0p[n0], gs1 = g0p[n1];
    ((float4*)s_gumb)[tid] = gst;
    if (tid < 4 * HH) {  // q = b1 + W1[:,DD:] @ ctx
      int row = tid >> 2, g = tid & 3;
      const float4* wr = (const float4*)&s_W1c[row][0] + g * 4;
      const float4* c4 = (const float4*)s_ctx + g * 4;
      float s = 0.f;
#pragma unroll
      for (int i = 0; i < 4; i++) {
        float4 w = wr[i], cc = c4[i];
        s += w.x * cc.x + w.y * cc.y + w.z * cc.z + w.w * cc.w;
      }
      s += __shfl_xor(s, 1);
      s += __shfl_xor(s, 2);
      if (g == 0) s_q[row] = s + s_b1[row];
    }
    if (tid >= 512 && tid < 512 + CSMAX) s_key[tid - 512] = 0ull;
    if (tid == 768) s_cnt = 0;
    __syncthreads();

    // ======== LOGITS + SEL0 scan ========
    {
      float l0 = s_b2v, l1 = s_b2v;
      const float4* p0 = P4 + (size_t)n0 * 16;
      const float4* p1 = P4 + (size_t)n1 * 16;
      const float4* q4 = (const float4*)s_q;
      const float4* w4 = (const float4*)s_W2;
#pragma unroll
      for (int qq = 0; qq < 16; qq += 4) {
        float4 A[4], Bv[4];
#pragma unroll
        for (int i = 0; i < 4; i++) { A[i] = p0[qq + i]; Bv[i] = p1[qq + i]; }
#pragma unroll
        for (int i = 0; i < 4; i++) {
          float4 qv = q4[qq + i], w = w4[qq + i];
          l0 += w.x * fmaxf(A[i].x + qv.x, 0.f) + w.y * fmaxf(A[i].y + qv.y, 0.f) +
                w.z * fmaxf(A[i].z + qv.z, 0.f) + w.w * fmaxf(A[i].w + qv.w, 0.f);
          l1 += w.x * fmaxf(Bv[i].x + qv.x, 0.f) + w.y * fmaxf(Bv[i].y + qv.y, 0.f) +
                w.z * fmaxf(Bv[i].z + qv.z, 0.f) + w.w * fmaxf(Bv[i].w + qv.w, 0.f);
        }
      }
      s_logits[n0] = l0;
      s_logits[n1] = l1;
      float bv = -FLT_MAX;
      int bi = NB;
      if (s_avail[n0]) { float y = l0 + gs0; if (y > bv) { bv = y; bi = n0; } }
      if (s_avail[n1]) { float y = l1 + gs1; if (y > bv || (y == bv && n1 < bi)) { bv = y; bi = n1; } }
      scanReduce(bv, bi, 0);
    }
    __syncthreads();

    // ======== H0: seed row -> reach + frontier ========
    const int seed = decodeIdx(s_key[0]);
    if (tid < 512) {
      if (seed >= 0) {
        float4 a = adj4[(size_t)seed * 512 + tid];
        int m = tid << 2;
        unsigned f0 = a.x > 0.f, f1 = a.y > 0.f, f2 = a.z > 0.f, f3 = a.w > 0.f;
        unsigned r = f0 | (f1 << 8) | (f2 << 16) | (f3 << 24);
        if ((seed >> 2) == tid) r |= 1u << ((seed & 3) * 8);
        ((unsigned*)s_reach)[tid] = r;
        if (f0 && m != seed)     { int p = atomicAdd(&s_cnt, 1); if (p < 128) s_list[p] = (short)m; }
        if (f1 && m + 1 != seed) { int p = atomicAdd(&s_cnt, 1); if (p < 128) s_list[p] = (short)(m + 1); }
        if (f2 && m + 2 != seed) { int p = atomicAdd(&s_cnt, 1); if (p < 128) s_list[p] = (short)(m + 2); }
        if (f3 && m + 3 != seed) { int p = atomicAdd(&s_cnt, 1); if (p < 128) s_list[p] = (short)(m + 3); }
      } else {
        ((unsigned*)s_reach)[tid] = 0u;
      }
    }
    __syncthreads();

    // ======== H1: OR frontier rows into reach ========
    if (seed >= 0) {
      int cnt = min(s_cnt, 128);
      int m4 = tid & 511, rg = tid >> 9;
      bool a0 = false, a1 = false, a2 = false, a3 = false;
#pragma unroll
      for (int k = 0; k < 20; k++) {
        int li = rg + 2 * k;
        if (li < cnt) {
          int n = s_list[li];
          float4 a = adj4[(size_t)n * 512 + m4];
          a0 |= a.x > 0.f; a1 |= a.y > 0.f; a2 |= a.z > 0.f; a3 |= a.w > 0.f;
        }
      }
      for (int li = rg + 40; li < cnt; li += 2) {
        int n = s_list[li];
        float4 a = adj4[(size_t)n * 512 + m4];
        a0 |= a.x > 0.f; a1 |= a.y > 0.f; a2 |= a.z > 0.f; a3 |= a.w > 0.f;
      }
      int m = m4 << 2;
      if (a0) s_reach[m] = 1;
      if (a1) s_reach[m + 1] = 1;
      if (a2) s_reach[m + 2] = 1;
      if (a3) s_reach[m + 3] = 1;
    }
    __syncthreads();

    // ======== SEL1 ========
    {
      float bv = -FLT_MAX;
      int bi = NB;
#pragma unroll
      for (int r = 0; r < 2; r++) {
        int n = tid + r * NT;
        if (s_avail[n] && s_reach[n] && n != seed) {
          float y = s_logits[n] + s_gumb[0][n];
          if (y > bv || (y == bv && n < bi)) { bv = y; bi = n; }
        }
      }
      scanReduce(bv, bi, 1);
    }
    __syncthreads();

    // ======== SEL2 ========
    const int w1i = decodeIdx(s_key[1]);
    {
      float bv = -FLT_MAX;
      int bi = NB;
#pragma unroll
      for (int r = 0; r < 2; r++) {
        int n = tid + r * NT;
        if (s_avail[n] && s_reach[n] && n != seed && n != w1i) {
          float y = s_logits[n] + s_gumb[1][n];
          if (y > bv || (y == bv && n < bi)) { bv = y; bi = n; }
        }
      }
      scanReduce(bv, bi, 2);
    }
    __syncthreads();

    // ======== E: emb || avail/assign update ========
    const int w2i = decodeIdx(s_key[2]);
    {
      int mc = (seed >= 0) + (w1i >= 0) + (w2i >= 0);
      if (tid < DD) {
        float acc = 0.f;
        if (seed >= 0) acc += x[xb + (size_t)seed * DD + tid];
        if (w1i >= 0) acc += x[xb + (size_t)w1i * DD + tid];
        if (w2i >= 0) acc += x[xb + (size_t)w2i * DD + tid];
        float e = acc / fmaxf((float)mc, 1.0f);
        s_hist[c][tid] = e;
        out_feat[((size_t)b * MAXC + c) * DD + tid] = e;
      } else if (tid >= 512 && tid < 512 + CSMAX) {
        int idx = (tid == 512) ? seed : (tid == 513 ? w1i : w2i);
        if (idx >= 0) { s_avail[idx] = 0; s_assignB[idx] |= (unsigned char)(1 << c); }
      }
    }
    __syncthreads();

    // ======== G: gi = bih + Wih @ hist[c] ========
    if (tid < 4 * 3 * HH) {
      int row = tid >> 2, g = tid & 3;
      const float4* wr = (const float4*)(Wih + (size_t)row * DD) + g * 8;
      const float4* h4 = (const float4*)s_hist[c] + g * 8;
      float s = 0.f;
#pragma unroll
      for (int i = 0; i < 8; i++) {
        float4 w = wr[i], hh = h4[i];
        s += w.x * hh.x + w.y * hh.y + w.z * hh.z + w.w * hh.w;
      }
      s += __shfl_xor(s, 1);
      s += __shfl_xor(s, 2);
      if (g == 0) s_giAll[c][row] = s + bih[row];
    }
    __syncthreads();

    // ======== GRU over history 0..c (1 barrier/step, double-buffered h) ========
    for (int t0 = 0; t0 <= c; t0++) {
      if (tid < 4 * HH) {
        int row = tid >> 2, g = tid & 3;
        const float4* h4 = (const float4*)s_h[hp] + g * 4;
        float4 hv[4];
#pragma unroll
        for (int i = 0; i < 4; i++) hv[i] = h4[i];
        const float4* wr = (const float4*)&s_Whh[row][0] + g * 4;
        const float4* wz = (const float4*)&s_Whh[HH + row][0] + g * 4;
        const float4* wn = (const float4*)&s_Whh[2 * HH + row][0] + g * 4;
        float sr = 0.f, sz = 0.f, sn = 0.f;
#pragma unroll
        for (int i = 0; i < 4; i++) {
          float4 a = wr[i], bz = wz[i], cn = wn[i], h = hv[i];
          sr += a.x * h.x + a.y * h.y + a.z * h.z + a.w * h.w;
          sz += bz.x * h.x + bz.y * h.y + bz.z * h.z + bz.w * h.w;
          sn += cn.x * h.x + cn.y * h.y + cn.z * h.z + cn.w * h.w;
        }
        sr += __shfl_xor(sr, 1); sr += __shfl_xor(sr, 2);
        sz += __shfl_xor(sz, 1); sz += __shfl_xor(sz, 2);
        sn += __shfl_xor(sn, 1); sn += __shfl_xor(sn, 2);
        if (g == 0) {
          float r = 1.f / (1.f + expf(-(s_giAll[t0][row] + sr + s_bhh[row])));
          float z = 1.f / (1.f + expf(-(s_giAll[t0][HH + row] + sz + s_bhh[HH + row])));
          float nn = tanhf(s_giAll[t0][2 * HH + row] + r * (sn + s_bhh[2 * HH + row]));
          float hn = (1.f - z) * nn + z * s_h[hp][row];
          s_h[hp ^ 1][row] = hn;
          if (t0 == c) s_ctx[row] = hn;
        }
      }
      hp ^= 1;
      __syncthreads();
    }
  }  // clusters

  // ======== final coalesced assign + cluster_adj writes ========
#pragma unroll
  for (int r = 0; r < 2; r++) {
    int n = tid + r * NT;
    unsigned bits = s_assignB[n];
    size_t base = ((size_t)(b * NB + n)) * MAXC;
#pragma unroll
    for (int cc = 0; cc < MAXC; cc++)
      out_assign[base + cc] = (float)((bits >> cc) & 1u);
  }
  for (int i = tid; i < MAXC * MAXC; i += NT)
    out_adjm[(size_t)b * MAXC * MAXC + i] = ((i / MAXC) == (i % MAXC)) ? 0.f : 1.f;
}

extern "C" void kernel_launch(void* const* d_in, const int* in_sizes, int n_in,
                              void* d_out, int out_size, void* d_ws, size_t ws_size,
                              hipStream_t stream) {
  const float* x   = (const float*)d_in[0];
  const float* adj = (const float*)d_in[1];
  const int*   mask= (const int*)d_in[2];
  const float* W1  = (const float*)d_in[3];
  const float* b1  = (const float*)d_in[4];
  const float* W2  = (const float*)d_in[5];
  const float* b2  = (const float*)d_in[6];
  const float* Wc  = (const float*)d_in[7];
  const float* bc  = (const float*)d_in[8];
  const float* Wih = (const float*)d_in[9];
  const float* Whh = (const float*)d_in[10];
  const float* bih = (const float*)d_in[11];
  const float* bhh = (const float*)d_in[12];

  float* ws = (float*)d_ws;
  float* P       = ws;                                   // [B*N*HH]  8 MB
  float* partial = P + (size_t)BB * NB * HH;             // [B][16][DD]
  float* gumb    = partial + (size_t)BB * 16 * DD;       // [15][B][N]

  float* out = (float*)d_out;
  float* out_feat = out;                                     // [B,5,D]
  float* out_adjm = out + (size_t)BB * MAXC * DD;            // [B,5,5]
  float* out_assign = out_adjm + (size_t)BB * MAXC * MAXC;   // [B,N,5]

  hipLaunchKernelGGL(gvp_prep, dim3(504), dim3(NT), 0, stream, x, W1, P, partial, gumb);
  hipLaunchKernelGGL(gvp_main, dim3(BB * REP), dim3(NT), 0, stream,
                     x, adj, mask, W1, b1, W2, b2, Wc, bc, Wih, Whh, bih, bhh, P, partial, gumb,
                     out_feat, out_adjm, out_assign);
}